// Round 12
// baseline (2971.225 us; speedup 1.0000x reference)
//
#include <hip/hip_runtime.h>
#include <hip/hip_fp16.h>
#include <cstddef>

#define TT 2048   // time steps
#define BB 256    // batch
#define DD 32     // input dim
#define HH 64     // hidden
#define GG 256    // 4*H
#define RPB 2     // batch rows per block

__device__ __forceinline__ float sigmf(float v)  { return 1.0f / (1.0f + __expf(-v)); }
__device__ __forceinline__ float tanhf_(float v) { return 2.0f / (1.0f + __expf(-2.0f * v)) - 1.0f; }

// TWO independent R8-engines per block (1024 threads, 16 waves = 4/SIMD).
// Row r = tid>>9 runs the proven R8 pipeline (waves 0-3: layer-1 one step
// ahead; waves 4-7: layer-2 + projection) on batch row blockIdx*2+r with its
// own LDS state. Both rows share the barrier (identical schedules), so when
// row A's waves sit in barrier/LDS/dep stalls, row B's waves issue -- R11
// proved 4 waves/SIMD reaches ~77% VALU util; this gets that util WITHOUT
// R11's +64% instruction bloat (per-row issue stays exactly R8's).
__global__ __launch_bounds__(1024, 1)
void dlstm_kernel(const float* __restrict__ x,
                  const float* __restrict__ W1, const float* __restrict__ U1,
                  const float* __restrict__ b1,
                  const float* __restrict__ W2, const float* __restrict__ U2,
                  const float* __restrict__ b2,
                  const float* __restrict__ Wd, const float* __restrict__ bd,
                  float* __restrict__ out)
{
    const int tid = threadIdx.x;
    const int r   = tid >> 9;               // row slot within block (0/1)
    const int t   = tid & 511;              // thread id within the row-engine
    const int b   = blockIdx.x * RPB + r;   // batch row
    const int wid = t >> 6, l = t & 63;
    const int kq  = l >> 4, ul = l & 15;

    __shared__ __align__(16) __half h1b[RPB][2][HH];
    __shared__ __align__(16) __half h2b[RPB][2][HH];
    __shared__ float pbuf[RPB][2][4];

    if (t < HH) {
        h1b[r][0][t] = __float2half(0.f); h1b[r][1][t] = __float2half(0.f);
        h2b[r][0][t] = __float2half(0.f); h2b[r][1][t] = __float2half(0.f);
    }
    if (t < 8) pbuf[r][t >> 2][t & 3] = 0.f;
    __syncthreads();

    if (wid < 4) {
        // ================= layer-1 engine: computes h1(n) at iter n =================
        const int u = (wid << 4) + ul;
        __half2 u1p[4][8];
        #pragma unroll
        for (int gp = 0; gp < 4; ++gp)
            #pragma unroll
            for (int j = 0; j < 8; ++j)
                u1p[gp][j] = __floats2half2_rn(U1[(kq*16 + 2*j    ) * GG + gp*HH + u],
                                               U1[(kq*16 + 2*j + 1) * GG + gp*HH + u]);
        __half2 w1p[4][4];
        #pragma unroll
        for (int gp = 0; gp < 4; ++gp)
            #pragma unroll
            for (int j = 0; j < 4; ++j)
                w1p[gp][j] = __floats2half2_rn(W1[(kq*8 + 2*j    ) * GG + gp*HH + u],
                                               W1[(kq*8 + 2*j + 1) * GG + gp*HH + u]);
        const float b1k = b1[kq * HH + u];
        const float bd0 = bd[0];
        float c1 = 0.f;

        const float* xr = x + (size_t)b * TT * DD + kq * 8;   // my 8 x-rows
        float4 xa = *(const float4*)(xr);
        float4 xb = *(const float4*)(xr + 4);

        for (int n = 0; n < TT + 2; ++n) {
            const int p = n & 1;
            if (n < TT) {
                const size_t tn = (n + 1 < TT) ? (size_t)(n + 1) : (size_t)n;
                float4 na = *(const float4*)(xr + tn * DD);
                float4 nb = *(const float4*)(xr + tn * DD + 4);

                __half2 xx[4];
                xx[0] = __floats2half2_rn(xa.x, xa.y);
                xx[1] = __floats2half2_rn(xa.z, xa.w);
                xx[2] = __floats2half2_rn(xb.x, xb.y);
                xx[3] = __floats2half2_rn(xb.z, xb.w);

                const __half2* hp = (const __half2*)&h1b[r][p][kq * 16];
                __half2 hh[8];
                #pragma unroll
                for (int j = 0; j < 8; ++j) hh[j] = hp[j];

                float ag[4];
                #pragma unroll
                for (int gp = 0; gp < 4; ++gp) {
                    __half2 s = __float2half2_rn(0.f);
                    #pragma unroll
                    for (int j = 0; j < 8; ++j) s = __hfma2(u1p[gp][j], hh[j], s);
                    #pragma unroll
                    for (int j = 0; j < 4; ++j) s = __hfma2(w1p[gp][j], xx[j], s);
                    ag[gp] = __low2float(s) + __high2float(s);
                }
                // combine across kq: lane ends with z-total of gate kq (R5/R8-verified)
                float t1 = (kq & 1) ? ag[0] : ag[1];
                float t2 = (kq & 1) ? ag[2] : ag[3];
                float r1 = __shfl_xor(t1, 16, 64);
                float r2 = __shfl_xor(t2, 16, 64);
                float m1 = (kq & 1) ? ag[1] : ag[0];
                float m2 = (kq & 1) ? ag[3] : ag[2];
                float s1 = m1 + r1, s2 = m2 + r2;
                float t3 = (kq < 2) ? s2 : s1;
                float r3 = __shfl_xor(t3, 32, 64);
                float mine = (kq < 2) ? s1 : s2;
                float z = mine + r3 + b1k;

                float a = (kq == 2) ? tanhf_(z) : sigmf(z);
                float g16 = __shfl_xor(a, 16, 64);
                float g32 = __shfl_xor(a, 32, 64);
                float g48 = __shfl_xor(g16, 32, 64);
                c1 = g16 * c1 + a * g32;         // kq0 roles: i=a f=g16 c~=g32 o=g48
                float h = g48 * tanhf_(c1);
                if (kq == 0) h1b[r][p ^ 1][u] = __float2half(h);

                xa = na; xb = nb;
            }
            // out(n-2): partials written by L2 at iter n-1
            if (t == 0 && n >= 2) {
                float s = pbuf[r][p][0] + pbuf[r][p][1] + pbuf[r][p][2] + pbuf[r][p][3];
                out[(size_t)b * TT + (n - 2)] = sigmf(s + bd0);
            }
            __syncthreads();
        }
    } else {
        // ================= layer-2 engine: computes h2(n-1) at iter n =================
        const int w2i = wid - 4;
        const int u = (w2i << 4) + ul;
        __half2 w2p[4][8], u2p[4][8];
        #pragma unroll
        for (int gp = 0; gp < 4; ++gp)
            #pragma unroll
            for (int j = 0; j < 8; ++j) {
                w2p[gp][j] = __floats2half2_rn(W2[(kq*16 + 2*j    ) * GG + gp*HH + u],
                                               W2[(kq*16 + 2*j + 1) * GG + gp*HH + u]);
                u2p[gp][j] = __floats2half2_rn(U2[(kq*16 + 2*j    ) * GG + gp*HH + u],
                                               U2[(kq*16 + 2*j + 1) * GG + gp*HH + u]);
            }
        const float b2k = b2[kq * HH + u];
        const float wdu = Wd[u];
        float c2 = 0.f;

        for (int n = 0; n < TT + 2; ++n) {
            const int p = n & 1;
            if (n >= 1 && n <= TT) {
                const __half2* h1p = (const __half2*)&h1b[r][p][kq * 16];
                const __half2* h2p = (const __half2*)&h2b[r][p][kq * 16];
                __half2 hh1[8], hh2[8];
                #pragma unroll
                for (int j = 0; j < 8; ++j) { hh1[j] = h1p[j]; hh2[j] = h2p[j]; }

                float ag[4];
                #pragma unroll
                for (int gp = 0; gp < 4; ++gp) {
                    __half2 s = __float2half2_rn(0.f);
                    #pragma unroll
                    for (int j = 0; j < 8; ++j) s = __hfma2(w2p[gp][j], hh1[j], s);
                    #pragma unroll
                    for (int j = 0; j < 8; ++j) s = __hfma2(u2p[gp][j], hh2[j], s);
                    ag[gp] = __low2float(s) + __high2float(s);
                }
                float t1 = (kq & 1) ? ag[0] : ag[1];
                float t2 = (kq & 1) ? ag[2] : ag[3];
                float r1 = __shfl_xor(t1, 16, 64);
                float r2 = __shfl_xor(t2, 16, 64);
                float m1 = (kq & 1) ? ag[1] : ag[0];
                float m2 = (kq & 1) ? ag[3] : ag[2];
                float s1 = m1 + r1, s2 = m2 + r2;
                float t3 = (kq < 2) ? s2 : s1;
                float r3 = __shfl_xor(t3, 32, 64);
                float mine = (kq < 2) ? s1 : s2;
                float z = mine + r3 + b2k;

                float a = (kq == 2) ? tanhf_(z) : sigmf(z);
                float g16 = __shfl_xor(a, 16, 64);
                float g32 = __shfl_xor(a, 32, 64);
                float g48 = __shfl_xor(g16, 32, 64);
                c2 = g16 * c2 + a * g32;         // kq0 roles
                float h = g48 * tanhf_(c2);
                if (kq == 0) h2b[r][p ^ 1][u] = __float2half(h);

                // projection partial: only kq0 lanes contribute real h
                float v = (kq == 0) ? h * wdu : 0.f;
                v += __shfl_xor(v, 1, 64);
                v += __shfl_xor(v, 2, 64);
                v += __shfl_xor(v, 4, 64);
                v += __shfl_xor(v, 8, 64);
                if (l == 0) pbuf[r][p ^ 1][w2i] = v;
            }
            __syncthreads();
        }
    }
}

extern "C" void kernel_launch(void* const* d_in, const int* in_sizes, int n_in,
                              void* d_out, int out_size, void* d_ws, size_t ws_size,
                              hipStream_t stream) {
    const float* x  = (const float*)d_in[0];
    const float* W1 = (const float*)d_in[1];
    const float* U1 = (const float*)d_in[2];
    const float* b1 = (const float*)d_in[3];
    const float* W2 = (const float*)d_in[4];
    const float* U2 = (const float*)d_in[5];
    const float* b2 = (const float*)d_in[6];
    const float* Wd = (const float*)d_in[7];
    const float* bd = (const float*)d_in[8];
    float* out = (float*)d_out;

    dlstm_kernel<<<dim3(BB / RPB), dim3(1024), 0, stream>>>(
        x, W1, U1, b1, W2, U2, b2, Wd, bd, out);
}

// Round 13
// 2056.831 us; speedup vs baseline: 1.4446x; 1.4446x over previous
//
#include <hip/hip_runtime.h>
#include <hip/hip_fp16.h>
#include <cstddef>

#define TT 2048   // time steps
#define BB 256    // batch
#define DD 32     // input dim
#define HH 64     // hidden
#define GG 256    // 4*H

__device__ __forceinline__ float sigmf(float v)  { return 1.0f / (1.0f + __expf(-v)); }
__device__ __forceinline__ float tanhf_(float v) { return 2.0f / (1.0f + __expf(-2.0f * v)) - 1.0f; }
// single-sigmoid branchless activation: tanh(z) = 2*sigm(2z)-1 (one exp+rcp)
__device__ __forceinline__ float act(float z, bool istanh) {
    float zin = istanh ? z + z : z;
    float s = 1.0f / (1.0f + __expf(-zin));
    return istanh ? 2.0f * s - 1.0f : s;
}

// Barrier with LDS-only drain: __syncthreads() emits s_waitcnt vmcnt(0)
// lgkmcnt(0) before s_barrier, force-draining the in-flight global prefetch
// every step (serializes HBM/L3 latency into the recurrence). The h-exchange
// only needs LDS ordering -> wait lgkmcnt(0) only; each wave's global loads
// are waited by the compiler at their consumption point.
#define LDS_BARRIER() asm volatile("s_waitcnt lgkmcnt(0)\n\ts_barrier" ::: "memory")

// ---------------- pre-kernel: zx[(b*TT+t)*256 + u*4+g] = x[b,t,:]·W1[:,g*64+u] + b1, f16 ----------------
// (validated in R10: absmax 0.0039 through this path)
__global__ __launch_bounds__(256)
void zx_pre(const float* __restrict__ x, const float* __restrict__ W1,
            const float* __restrict__ b1, __half* __restrict__ zx)
{
    const int bb = blockIdx.x, tb = blockIdx.y, zr = threadIdx.x;  // zr = u*4+g
    __shared__ float xs[8][DD];
    const float* xb = x + ((size_t)bb * TT + (size_t)tb * 8) * DD;
    xs[zr >> 5][zr & 31] = xb[zr];
    __syncthreads();

    const int u = zr >> 2, g = zr & 3;
    const int colW = g * HH + u;
    float wcol[DD];
    #pragma unroll
    for (int d = 0; d < DD; ++d) wcol[d] = W1[d * GG + colW];
    const float bias = b1[colW];

    __half* zb = zx + ((size_t)bb * TT + (size_t)tb * 8) * 256 + zr;
    #pragma unroll
    for (int r8 = 0; r8 < 8; ++r8) {
        float z0 = bias, z1 = 0.f, z2 = 0.f, z3 = 0.f;
        #pragma unroll
        for (int d = 0; d < DD; d += 4) {
            z0 += xs[r8][d+0] * wcol[d+0];
            z1 += xs[r8][d+1] * wcol[d+1];
            z2 += xs[r8][d+2] * wcol[d+2];
            z3 += xs[r8][d+3] * wcol[d+3];
        }
        zb[(size_t)r8 * 256] = __float2half((z0 + z1) + (z2 + z3));
    }
}

// ---------------- recurrence: R8 engine + zx + LDS-only barrier + single-act ----------------
// One block per batch row; 512 threads = 8 waves. Waves 0-3: layer-1 (one step
// ahead); waves 4-7: layer-2 + projection. Thread: unit u = wid*16+(l&15),
// K-quarter kq = l>>4; all 4 gates of u over the K-chunk; combine = 3 shfl_xor;
// gather = 3 shfl_xor; cell update in kq0 roles. One LDS_BARRIER per step.
__global__ __launch_bounds__(512, 2)
void dlstm_rec(const __half* __restrict__ zx,
               const float* __restrict__ U1,
               const float* __restrict__ W2, const float* __restrict__ U2,
               const float* __restrict__ b2,
               const float* __restrict__ Wd, const float* __restrict__ bd,
               float* __restrict__ out)
{
    const int tid = threadIdx.x, b = blockIdx.x;
    const int wid = tid >> 6, l = tid & 63;
    const int kq = l >> 4, ul = l & 15;
    const bool istanh = (kq == 2);

    __shared__ __align__(16) __half h1b[2][HH];
    __shared__ __align__(16) __half h2b[2][HH];
    __shared__ float pbuf[2][4];

    if (tid < HH) {
        h1b[0][tid] = __float2half(0.f); h1b[1][tid] = __float2half(0.f);
        h2b[0][tid] = __float2half(0.f); h2b[1][tid] = __float2half(0.f);
    }
    if (tid < 8) pbuf[tid >> 2][tid & 3] = 0.f;
    __syncthreads();

    if (wid < 4) {
        // ================= layer-1 engine: computes h1(n) at iter n =================
        const int u = (wid << 4) + ul;
        __half2 u1p[4][8];
        #pragma unroll
        for (int gp = 0; gp < 4; ++gp)
            #pragma unroll
            for (int j = 0; j < 8; ++j)
                u1p[gp][j] = __floats2half2_rn(U1[(kq*16 + 2*j    ) * GG + gp*HH + u],
                                               U1[(kq*16 + 2*j + 1) * GG + gp*HH + u]);
        const float bd0 = bd[0];
        float c1 = 0.f;

        // zx for MY gate kq of MY unit u (bias pre-folded)
        const __half* zr_ = zx + (size_t)b * TT * 256 + u * 4 + kq;
        __half zc = *zr_;

        for (int n = 0; n < TT + 2; ++n) {
            const int p = n & 1;
            if (n < TT) {
                const size_t tn = (n + 1 < TT) ? (size_t)(n + 1) : (size_t)n;
                __half znx = zr_[tn * 256];        // prefetch zx(n+1), stays in flight

                const __half2* hp = (const __half2*)&h1b[p][kq * 16];
                __half2 hh[8];
                #pragma unroll
                for (int j = 0; j < 8; ++j) hh[j] = hp[j];

                float ag[4];
                #pragma unroll
                for (int gp = 0; gp < 4; ++gp) {
                    __half2 s = __float2half2_rn(0.f);
                    #pragma unroll
                    for (int j = 0; j < 8; ++j) s = __hfma2(u1p[gp][j], hh[j], s);
                    ag[gp] = __low2float(s) + __high2float(s);
                }
                // combine across kq: lane ends with z-total of gate kq (R5/R8-verified)
                float t1 = (kq & 1) ? ag[0] : ag[1];
                float t2 = (kq & 1) ? ag[2] : ag[3];
                float r1 = __shfl_xor(t1, 16, 64);
                float r2 = __shfl_xor(t2, 16, 64);
                float m1 = (kq & 1) ? ag[1] : ag[0];
                float m2 = (kq & 1) ? ag[3] : ag[2];
                float s1 = m1 + r1, s2 = m2 + r2;
                float t3 = (kq < 2) ? s2 : s1;
                float r3 = __shfl_xor(t3, 32, 64);
                float mine = (kq < 2) ? s1 : s2;
                float z = mine + r3 + __half2float(zc);

                float a = act(z, istanh);
                float g16 = __shfl_xor(a, 16, 64);
                float g32 = __shfl_xor(a, 32, 64);
                float g48 = __shfl_xor(g16, 32, 64);
                c1 = g16 * c1 + a * g32;         // kq0 roles: i=a f=g16 c~=g32 o=g48
                float h = g48 * tanhf_(c1);
                if (kq == 0) h1b[p ^ 1][u] = __float2half(h);

                zc = znx;
            }
            // out(n-2): partials written by L2 at iter n-1
            if (tid == 0 && n >= 2) {
                float s = pbuf[p][0] + pbuf[p][1] + pbuf[p][2] + pbuf[p][3];
                out[(size_t)b * TT + (n - 2)] = sigmf(s + bd0);
            }
            LDS_BARRIER();
        }
    } else {
        // ================= layer-2 engine: computes h2(n-1) at iter n =================
        const int w2i = wid - 4;
        const int u = (w2i << 4) + ul;
        __half2 w2p[4][8], u2p[4][8];
        #pragma unroll
        for (int gp = 0; gp < 4; ++gp)
            #pragma unroll
            for (int j = 0; j < 8; ++j) {
                w2p[gp][j] = __floats2half2_rn(W2[(kq*16 + 2*j    ) * GG + gp*HH + u],
                                               W2[(kq*16 + 2*j + 1) * GG + gp*HH + u]);
                u2p[gp][j] = __floats2half2_rn(U2[(kq*16 + 2*j    ) * GG + gp*HH + u],
                                               U2[(kq*16 + 2*j + 1) * GG + gp*HH + u]);
            }
        const float b2k = b2[kq * HH + u];
        const float wdu = Wd[u];
        float c2 = 0.f;

        for (int n = 0; n < TT + 2; ++n) {
            const int p = n & 1;
            if (n >= 1 && n <= TT) {
                const __half2* h1p = (const __half2*)&h1b[p][kq * 16];
                const __half2* h2p = (const __half2*)&h2b[p][kq * 16];
                __half2 hh1[8], hh2[8];
                #pragma unroll
                for (int j = 0; j < 8; ++j) { hh1[j] = h1p[j]; hh2[j] = h2p[j]; }

                float ag[4];
                #pragma unroll
                for (int gp = 0; gp < 4; ++gp) {
                    __half2 s = __float2half2_rn(0.f);
                    #pragma unroll
                    for (int j = 0; j < 8; ++j) s = __hfma2(w2p[gp][j], hh1[j], s);
                    #pragma unroll
                    for (int j = 0; j < 8; ++j) s = __hfma2(u2p[gp][j], hh2[j], s);
                    ag[gp] = __low2float(s) + __high2float(s);
                }
                float t1 = (kq & 1) ? ag[0] : ag[1];
                float t2 = (kq & 1) ? ag[2] : ag[3];
                float r1 = __shfl_xor(t1, 16, 64);
                float r2 = __shfl_xor(t2, 16, 64);
                float m1 = (kq & 1) ? ag[1] : ag[0];
                float m2 = (kq & 1) ? ag[3] : ag[2];
                float s1 = m1 + r1, s2 = m2 + r2;
                float t3 = (kq < 2) ? s2 : s1;
                float r3 = __shfl_xor(t3, 32, 64);
                float mine = (kq < 2) ? s1 : s2;
                float z = mine + r3 + b2k;

                float a = act(z, istanh);
                float g16 = __shfl_xor(a, 16, 64);
                float g32 = __shfl_xor(a, 32, 64);
                float g48 = __shfl_xor(g16, 32, 64);
                c2 = g16 * c2 + a * g32;         // kq0 roles
                float h = g48 * tanhf_(c2);
                if (kq == 0) h2b[p ^ 1][u] = __float2half(h);

                // projection partial: only kq0 lanes contribute real h
                float v = (kq == 0) ? h * wdu : 0.f;
                v += __shfl_xor(v, 1, 64);
                v += __shfl_xor(v, 2, 64);
                v += __shfl_xor(v, 4, 64);
                v += __shfl_xor(v, 8, 64);
                if (l == 0) pbuf[p ^ 1][w2i] = v;
            }
            LDS_BARRIER();
        }
    }
}

// ---------------- fallback: R8 kernel (1921us proven) if ws too small ----------------
__global__ __launch_bounds__(512, 2)
void dlstm_fb(const float* __restrict__ x,
              const float* __restrict__ W1, const float* __restrict__ U1,
              const float* __restrict__ b1,
              const float* __restrict__ W2, const float* __restrict__ U2,
              const float* __restrict__ b2,
              const float* __restrict__ Wd, const float* __restrict__ bd,
              float* __restrict__ out)
{
    const int tid = threadIdx.x, b = blockIdx.x;
    const int wid = tid >> 6, l = tid & 63;
    const int kq = l >> 4, ul = l & 15;

    __shared__ __align__(16) __half h1b[2][HH];
    __shared__ __align__(16) __half h2b[2][HH];
    __shared__ float pbuf[2][4];

    if (tid < HH) {
        h1b[0][tid] = __float2half(0.f); h1b[1][tid] = __float2half(0.f);
        h2b[0][tid] = __float2half(0.f); h2b[1][tid] = __float2half(0.f);
    }
    if (tid < 8) pbuf[tid >> 2][tid & 3] = 0.f;
    __syncthreads();

    if (wid < 4) {
        const int u = (wid << 4) + ul;
        __half2 u1p[4][8];
        #pragma unroll
        for (int gp = 0; gp < 4; ++gp)
            #pragma unroll
            for (int j = 0; j < 8; ++j)
                u1p[gp][j] = __floats2half2_rn(U1[(kq*16 + 2*j) * GG + gp*HH + u],
                                               U1[(kq*16 + 2*j + 1) * GG + gp*HH + u]);
        __half2 w1p[4][4];
        #pragma unroll
        for (int gp = 0; gp < 4; ++gp)
            #pragma unroll
            for (int j = 0; j < 4; ++j)
                w1p[gp][j] = __floats2half2_rn(W1[(kq*8 + 2*j) * GG + gp*HH + u],
                                               W1[(kq*8 + 2*j + 1) * GG + gp*HH + u]);
        const float b1k = b1[kq * HH + u];
        const float bd0 = bd[0];
        float c1 = 0.f;
        const float* xr = x + (size_t)b * TT * DD + kq * 8;
        float4 xa = *(const float4*)(xr);
        float4 xb = *(const float4*)(xr + 4);

        for (int n = 0; n < TT + 2; ++n) {
            const int p = n & 1;
            if (n < TT) {
                const size_t tn = (n + 1 < TT) ? (size_t)(n + 1) : (size_t)n;
                float4 na = *(const float4*)(xr + tn * DD);
                float4 nb = *(const float4*)(xr + tn * DD + 4);
                __half2 xx[4];
                xx[0] = __floats2half2_rn(xa.x, xa.y);
                xx[1] = __floats2half2_rn(xa.z, xa.w);
                xx[2] = __floats2half2_rn(xb.x, xb.y);
                xx[3] = __floats2half2_rn(xb.z, xb.w);
                const __half2* hp = (const __half2*)&h1b[p][kq * 16];
                __half2 hh[8];
                #pragma unroll
                for (int j = 0; j < 8; ++j) hh[j] = hp[j];
                float ag[4];
                #pragma unroll
                for (int gp = 0; gp < 4; ++gp) {
                    __half2 s = __float2half2_rn(0.f);
                    #pragma unroll
                    for (int j = 0; j < 8; ++j) s = __hfma2(u1p[gp][j], hh[j], s);
                    #pragma unroll
                    for (int j = 0; j < 4; ++j) s = __hfma2(w1p[gp][j], xx[j], s);
                    ag[gp] = __low2float(s) + __high2float(s);
                }
                float t1 = (kq & 1) ? ag[0] : ag[1];
                float t2 = (kq & 1) ? ag[2] : ag[3];
                float r1 = __shfl_xor(t1, 16, 64);
                float r2 = __shfl_xor(t2, 16, 64);
                float m1 = (kq & 1) ? ag[1] : ag[0];
                float m2 = (kq & 1) ? ag[3] : ag[2];
                float s1 = m1 + r1, s2 = m2 + r2;
                float t3 = (kq < 2) ? s2 : s1;
                float r3 = __shfl_xor(t3, 32, 64);
                float mine = (kq < 2) ? s1 : s2;
                float z = mine + r3 + b1k;
                float a = (kq == 2) ? tanhf_(z) : sigmf(z);
                float g16 = __shfl_xor(a, 16, 64);
                float g32 = __shfl_xor(a, 32, 64);
                float g48 = __shfl_xor(g16, 32, 64);
                c1 = g16 * c1 + a * g32;
                float h = g48 * tanhf_(c1);
                if (kq == 0) h1b[p ^ 1][u] = __float2half(h);
                xa = na; xb = nb;
            }
            if (tid == 0 && n >= 2) {
                float s = pbuf[p][0] + pbuf[p][1] + pbuf[p][2] + pbuf[p][3];
                out[(size_t)b * TT + (n - 2)] = sigmf(s + bd0);
            }
            __syncthreads();
        }
    } else {
        const int w2i = wid - 4;
        const int u = (w2i << 4) + ul;
        __half2 w2p[4][8], u2p[4][8];
        #pragma unroll
        for (int gp = 0; gp < 4; ++gp)
            #pragma unroll
            for (int j = 0; j < 8; ++j) {
                w2p[gp][j] = __floats2half2_rn(W2[(kq*16 + 2*j) * GG + gp*HH + u],
                                               W2[(kq*16 + 2*j + 1) * GG + gp*HH + u]);
                u2p[gp][j] = __floats2half2_rn(U2[(kq*16 + 2*j) * GG + gp*HH + u],
                                               U2[(kq*16 + 2*j + 1) * GG + gp*HH + u]);
            }
        const float b2k = b2[kq * HH + u];
        const float wdu = Wd[u];
        float c2 = 0.f;

        for (int n = 0; n < TT + 2; ++n) {
            const int p = n & 1;
            if (n >= 1 && n <= TT) {
                const __half2* h1p = (const __half2*)&h1b[p][kq * 16];
                const __half2* h2p = (const __half2*)&h2b[p][kq * 16];
                __half2 hh1[8], hh2[8];
                #pragma unroll
                for (int j = 0; j < 8; ++j) { hh1[j] = h1p[j]; hh2[j] = h2p[j]; }
                float ag[4];
                #pragma unroll
                for (int gp = 0; gp < 4; ++gp) {
                    __half2 s = __float2half2_rn(0.f);
                    #pragma unroll
                    for (int j = 0; j < 8; ++j) s = __hfma2(w2p[gp][j], hh1[j], s);
                    #pragma unroll
                    for (int j = 0; j < 8; ++j) s = __hfma2(u2p[gp][j], hh2[j], s);
                    ag[gp] = __low2float(s) + __high2float(s);
                }
                float t1 = (kq & 1) ? ag[0] : ag[1];
                float t2 = (kq & 1) ? ag[2] : ag[3];
                float r1 = __shfl_xor(t1, 16, 64);
                float r2 = __shfl_xor(t2, 16, 64);
                float m1 = (kq & 1) ? ag[1] : ag[0];
                float m2 = (kq & 1) ? ag[3] : ag[2];
                float s1 = m1 + r1, s2 = m2 + r2;
                float t3 = (kq < 2) ? s2 : s1;
                float r3 = __shfl_xor(t3, 32, 64);
                float mine = (kq < 2) ? s1 : s2;
                float z = mine + r3 + b2k;
                float a = (kq == 2) ? tanhf_(z) : sigmf(z);
                float g16 = __shfl_xor(a, 16, 64);
                float g32 = __shfl_xor(a, 32, 64);
                float g48 = __shfl_xor(g16, 32, 64);
                c2 = g16 * c2 + a * g32;
                float h = g48 * tanhf_(c2);
                if (kq == 0) h2b[p ^ 1][u] = __float2half(h);
                float v = (kq == 0) ? h * wdu : 0.f;
                v += __shfl_xor(v, 1, 64);
                v += __shfl_xor(v, 2, 64);
                v += __shfl_xor(v, 4, 64);
                v += __shfl_xor(v, 8, 64);
                if (l == 0) pbuf[p ^ 1][w2i] = v;
            }
            __syncthreads();
        }
    }
}

extern "C" void kernel_launch(void* const* d_in, const int* in_sizes, int n_in,
                              void* d_out, int out_size, void* d_ws, size_t ws_size,
                              hipStream_t stream) {
    const float* x  = (const float*)d_in[0];
    const float* W1 = (const float*)d_in[1];
    const float* U1 = (const float*)d_in[2];
    const float* b1 = (const float*)d_in[3];
    const float* W2 = (const float*)d_in[4];
    const float* U2 = (const float*)d_in[5];
    const float* b2 = (const float*)d_in[6];
    const float* Wd = (const float*)d_in[7];
    const float* bd = (const float*)d_in[8];
    float* out = (float*)d_out;

    const size_t need_f16 = (size_t)BB * TT * GG * sizeof(__half);  // 268 MB (proven fits)

    if (ws_size >= need_f16) {
        __half* zxw = (__half*)d_ws;
        zx_pre<<<dim3(BB, TT / 8), dim3(256), 0, stream>>>(x, W1, b1, zxw);
        dlstm_rec<<<dim3(BB), dim3(512), 0, stream>>>(zxw, U1, W2, U2, b2, Wd, bd, out);
    } else {
        dlstm_fb<<<dim3(BB), dim3(512), 0, stream>>>(x, W1, U1, b1, W2, U2, b2, Wd, bd, out);
    }
}